// Round 2
// baseline (3923.244 us; speedup 1.0000x reference)
//
#include <hip/hip_runtime.h>

typedef float f32x4 __attribute__((ext_vector_type(4)));
typedef __bf16 bf16x8 __attribute__((ext_vector_type(8)));
typedef unsigned short u16;
typedef unsigned int u32;

#define VOCAB 50257
#define KDIM 1024
#define MROWS 2048
#define TSEQ 256
#define NBLK 64
#define LOGN ((size_t)MROWS * VOCAB)

__device__ __forceinline__ u16 f2bf(float f) {
    u32 u = __builtin_bit_cast(u32, f);
    u = (u + 0x7FFFu + ((u >> 16) & 1u)) >> 16;
    return (u16)u;
}

__device__ __forceinline__ float sigm(float x) { return 1.0f / (1.0f + __expf(-x)); }

// ---------------- conversions / small prep ----------------

__global__ void conv_bf16(const float4* __restrict__ in, ushort4* __restrict__ out, long n4) {
    long i = (long)blockIdx.x * blockDim.x + threadIdx.x;
    long stride = (long)gridDim.x * blockDim.x;
    for (; i < n4; i += stride) {
        float4 v = in[i];
        ushort4 o;
        o.x = f2bf(v.x); o.y = f2bf(v.y); o.z = f2bf(v.z); o.w = f2bf(v.w);
        out[i] = o;
    }
}

__global__ void bias_sum(const float* __restrict__ a, const float* __restrict__ b,
                         float* __restrict__ o) {
    int i = blockIdx.x * 256 + threadIdx.x;
    if (i < 4096) o[i] = a[i] + b[i];
}

__global__ __launch_bounds__(256) void gather_emb(const int* __restrict__ x,
                                                  const float* __restrict__ embW,
                                                  u16* __restrict__ out) {
    int m = blockIdx.x;
    int row = x[m];
    const float4* src = (const float4*)(embW + (size_t)row * KDIM);
    ushort4* dst = (ushort4*)(out + (size_t)m * KDIM);
    float4 v = src[threadIdx.x];
    ushort4 o;
    o.x = f2bf(v.x); o.y = f2bf(v.y); o.z = f2bf(v.z); o.w = f2bf(v.w);
    dst[threadIdx.x] = o;
}

// ---------------- bf16 MFMA GEMM (C = A * B^T + bias), BK=64, swizzled LDS ----------------

#define BM 128
#define BN 128
#define BK 64

__device__ __forceinline__ void gl_lds16(const u16* g, const u16* l) {
    __builtin_amdgcn_global_load_lds(
        (const __attribute__((address_space(1))) u32*)g,
        (__attribute__((address_space(3))) u32*)l, 16, 0, 0);
}

__global__ __launch_bounds__(256, 2)
void gemm_bt(const u16* __restrict__ A, const u16* __restrict__ Bm,
             const float* __restrict__ bias, float* __restrict__ C,
             int N, int Nb, int K, int ldc)
{
    __shared__ __align__(16) u16 As[BM * BK];   // 16 KB
    __shared__ __align__(16) u16 Bs[BN * BK];   // 16 KB
    const int tid  = threadIdx.x;
    const int lane = tid & 63;
    const int wid  = tid >> 6;

    // bijective XCD swizzle (T1, m204): consecutive ids within an XCD share B-panel
    const int gx  = gridDim.x;                 // M-tiles
    const int nwg = gx * gridDim.y;
    const int lin = blockIdx.y * gx + blockIdx.x;
    const int qq = nwg >> 3, rr = nwg & 7;
    const int xcd = lin & 7, idx = lin >> 3;
    const int neu = (xcd < rr) ? (xcd * (qq + 1) + idx)
                               : (rr * (qq + 1) + (xcd - rr) * qq + idx);
    const int bm = neu % gx;
    const int bn = neu / gx;

    const int wr = wid >> 1, wc = wid & 1;     // 2x2 waves, 64x64 each

    // staging: linear 16B-slot L = r*256 + tid; row=L>>3, physslot=L&7,
    // logical slot = phys ^ (row&7)  (pre-swizzled source, linear LDS dest)
    const u16* gA[4]; const u16* gB[4];
    const u16* ldsA[4]; const u16* ldsB[4];
#pragma unroll
    for (int r = 0; r < 4; ++r) {
        int L = r * 256 + tid;
        int row = L >> 3, ps = L & 7;
        int ls = ps ^ (row & 7);
        gA[r] = A + (size_t)(bm * BM + row) * K + ls * 8;
        int brow = bn * BN + row; brow = brow < Nb ? brow : Nb - 1;
        gB[r] = Bm + (size_t)brow * K + ls * 8;
        ldsA[r] = As + (r * 256 + wid * 64) * 8;   // wave-uniform base
        ldsB[r] = Bs + (r * 256 + wid * 64) * 8;
    }

    // fragment read offsets (swizzled): logical slot s = ks*4+ksl, phys = s ^ (row&7)
    const int lrow = lane & 15, ksl = lane >> 4;
    int aoff[4][2], boff[4][2];
#pragma unroll
    for (int i = 0; i < 4; ++i)
#pragma unroll
        for (int ks = 0; ks < 2; ++ks) {
            int ar = wr * 64 + i * 16 + lrow;
            aoff[i][ks] = ar * BK + (((ks * 4 + ksl) ^ (ar & 7)) * 8);
            int br = wc * 64 + i * 16 + lrow;
            boff[i][ks] = br * BK + (((ks * 4 + ksl) ^ (br & 7)) * 8);
        }

    f32x4 acc[4][4] = {};
    for (int kt = 0; kt < K; kt += BK) {
#pragma unroll
        for (int r = 0; r < 4; ++r) gl_lds16(gA[r] + kt, ldsA[r]);
#pragma unroll
        for (int r = 0; r < 4; ++r) gl_lds16(gB[r] + kt, ldsB[r]);
        __syncthreads();
        bf16x8 af[4][2], bfb[4][2];
#pragma unroll
        for (int i = 0; i < 4; ++i)
#pragma unroll
            for (int ks = 0; ks < 2; ++ks) {
                af[i][ks]  = *(const bf16x8*)(As + aoff[i][ks]);
                bfb[i][ks] = *(const bf16x8*)(Bs + boff[i][ks]);
            }
#pragma unroll
        for (int ks = 0; ks < 2; ++ks)
#pragma unroll
            for (int mi = 0; mi < 4; ++mi)
#pragma unroll
                for (int ni = 0; ni < 4; ++ni)
                    acc[mi][ni] = __builtin_amdgcn_mfma_f32_16x16x32_bf16(
                        af[mi][ks], bfb[ni][ks], acc[mi][ni], 0, 0, 0);
        __syncthreads();
    }

    // C/D layout: col = lane&15, row = (lane>>4)*4 + reg
    const int crl = lane >> 4, ccl = lane & 15;
    const int row0 = bm * BM + wr * 64, col0 = bn * BN + wc * 64;
#pragma unroll
    for (int ni = 0; ni < 4; ++ni) {
        int col = col0 + ni * 16 + ccl;
        if (col < N) {
            float bv = bias[col];
#pragma unroll
            for (int mi = 0; mi < 4; ++mi) {
                int row = row0 + mi * 16 + crl * 4;
                float* cp = C + (size_t)row * ldc + col;
#pragma unroll
                for (int r = 0; r < 4; ++r)
                    cp[(size_t)r * ldc] = acc[mi][ni][r] + bv;
            }
        }
    }
}

// ---------------- persistent LSTM: 64 blocks, grid-sync per step ----------------
// Block b owns h-columns [16b,16b+16). Wave q holds gate-quadrant q's Whh rows
// (16 rows x 1024 K) as persistent MFMA B-fragments in 128 VGPRs.

__global__ __launch_bounds__(256, 1)
void lstm_persist(const u16* __restrict__ Whh,     // [4096][1024] bf16
                  const float* __restrict__ xproj, // [2048][4096] f32
                  u16* __restrict__ hbuf,          // [2][16][1024] bf16 (zeroed)
                  u16* __restrict__ hall,          // [2048][1024] bf16
                  float* __restrict__ outTail,     // h[8][1024], c[8][1024] f32
                  u32* __restrict__ cnt)           // zeroed
{
    const int tid  = threadIdx.x;
    const int lane = tid & 63;
    const int wq   = tid >> 6;                 // gate quadrant (i,f,g,o)
    const int lrow = lane & 15, ksl = lane >> 4;
    const int colbase = blockIdx.x * 16;

    // persistent Whh fragments: 32 x bf16x8 = 128 VGPRs
    bf16x8 Bf[32];
    {
        const u16* bp = Whh + (size_t)(wq * 1024 + colbase + lrow) * KDIM + ksl * 8;
#pragma unroll
        for (int kk = 0; kk < 32; ++kk) Bf[kk] = *(const bf16x8*)(bp + kk * 32);
    }

    __shared__ float S[4][8][16];

    const bool upd = tid < 128;
    const int b8 = tid >> 4, c16 = tid & 15;   // valid when upd
    float creg = 0.f;
    float xp0 = 0.f, xp1 = 0.f, xp2 = 0.f, xp3 = 0.f;
    size_t xbase = 0;
    if (upd) {
        xbase = (size_t)b8 * TSEQ * 4096 + colbase + c16;
        xp0 = xproj[xbase];          xp1 = xproj[xbase + 1024];
        xp2 = xproj[xbase + 2048];   xp3 = xproj[xbase + 3072];
    }

    const u16* h0 = hbuf + lrow * KDIM + ksl * 8;
    const u16* h1 = h0 + 16 * KDIM;
    const bool arow = lrow < 8;

    for (int t = 0; t < TSEQ; ++t) {
        const u16* hc = (t & 1) ? h1 : h0;
        f32x4 aE = {}, aO = {};
#pragma unroll
        for (int kk = 0; kk < 32; kk += 2) {
            bf16x8 av0 = {}, av1 = {};
            if (arow) {
                av0 = *(const bf16x8*)(hc + kk * 32);
                av1 = *(const bf16x8*)(hc + kk * 32 + 32);
            }
            aE = __builtin_amdgcn_mfma_f32_16x16x32_bf16(av0, Bf[kk],     aE, 0, 0, 0);
            aO = __builtin_amdgcn_mfma_f32_16x16x32_bf16(av1, Bf[kk + 1], aO, 0, 0, 0);
        }
        if (ksl < 2) {
#pragma unroll
            for (int r = 0; r < 4; ++r)
                S[wq][ksl * 4 + r][lrow] = aE[r] + aO[r];   // D row=(ksl*4+r), col=lrow
        }
        __syncthreads();
        if (upd) {
            float gi = S[0][b8][c16] + xp0;
            float gf = S[1][b8][c16] + xp1;
            float gg = S[2][b8][c16] + xp2;
            float go = S[3][b8][c16] + xp3;
            float iv = sigm(gi), fv = sigm(gf), ov = sigm(go);
            float gv = tanhf(gg);
            creg = fv * creg + iv * gv;
            float hv = ov * tanhf(creg);
            u16 hb = f2bf(hv);
            hbuf[((t + 1) & 1) * (16 * KDIM) + b8 * KDIM + colbase + c16] = hb;
            hall[((size_t)b8 * TSEQ + t) * KDIM + colbase + c16] = hb;
            if (t == TSEQ - 1) {
                outTail[b8 * KDIM + colbase + c16] = hv;
                outTail[8192 + b8 * KDIM + colbase + c16] = creg;
            }
            int tn = (t + 1 < TSEQ) ? t + 1 : t;           // prefetch next xproj
            size_t xb = xbase + (size_t)tn * 4096;
            xp0 = xproj[xb];        xp1 = xproj[xb + 1024];
            xp2 = xproj[xb + 2048]; xp3 = xproj[xb + 3072];
        }
        __syncthreads();
        if (tid == 0)
            __hip_atomic_fetch_add(cnt, 1u, __ATOMIC_RELEASE, __HIP_MEMORY_SCOPE_AGENT);
        const u32 target = (u32)NBLK * (u32)(t + 1);
        while (__hip_atomic_load(cnt, __ATOMIC_ACQUIRE, __HIP_MEMORY_SCOPE_AGENT) < target)
            __builtin_amdgcn_s_sleep(2);
    }
}

// ---------------- log_softmax: 2-pass (online max+sum, then subtract) ----------------

__global__ __launch_bounds__(256)
void logsoftmax_rows(float* __restrict__ out) {
    const int m = blockIdx.x;
    float* row = out + (size_t)m * VOCAB;
    const int tid = threadIdx.x;
    __shared__ float smx[4], ssm[4], slse;

    const int head = (int)(((16 - ((uintptr_t)row & 15)) & 15) >> 2);
    const int nv = (VOCAB - head) >> 2;
    const int tail0 = head + nv * 4;
    const int ntail = VOCAB - tail0;
    const float4* rv = (const float4*)(row + head);

    float mx = -3.0e38f, s = 0.f;
    for (int i = tid; i < nv; i += 256) {
        float4 v = rv[i];
        float m4 = fmaxf(fmaxf(v.x, v.y), fmaxf(v.z, v.w));
        if (m4 > mx) { s *= __expf(mx - m4); mx = m4; }
        s += __expf(v.x - mx) + __expf(v.y - mx) + __expf(v.z - mx) + __expf(v.w - mx);
    }
    if (tid < head) {
        float v = row[tid];
        if (v > mx) { s *= __expf(mx - v); mx = v; }
        s += __expf(v - mx);
    }
    if (tid >= 64 && tid < 64 + ntail) {
        float v = row[tail0 + (tid - 64)];
        if (v > mx) { s *= __expf(mx - v); mx = v; }
        s += __expf(v - mx);
    }
#pragma unroll
    for (int off = 32; off > 0; off >>= 1) {
        float om = __shfl_xor(mx, off), os = __shfl_xor(s, off);
        float nm = fmaxf(mx, om);
        s = s * __expf(mx - nm) + os * __expf(om - nm);
        mx = nm;
    }
    if ((tid & 63) == 0) { smx[tid >> 6] = mx; ssm[tid >> 6] = s; }
    __syncthreads();
    if (tid == 0) {
        float M = fmaxf(fmaxf(smx[0], smx[1]), fmaxf(smx[2], smx[3]));
        float S4 = ssm[0] * __expf(smx[0] - M) + ssm[1] * __expf(smx[1] - M) +
                   ssm[2] * __expf(smx[2] - M) + ssm[3] * __expf(smx[3] - M);
        slse = M + __logf(S4);
    }
    __syncthreads();
    const float lse = slse;

    float4* wv = (float4*)(row + head);
    for (int i = tid; i < nv; i += 256) {
        float4 v = rv[i];
        v.x -= lse; v.y -= lse; v.z -= lse; v.w -= lse;
        wv[i] = v;
    }
    if (tid < head) row[tid] -= lse;
    if (tid >= 64 && tid < 64 + ntail) row[tail0 + (tid - 64)] -= lse;
}

// ---------------- host ----------------

extern "C" void kernel_launch(void* const* d_in, const int* in_sizes, int n_in,
                              void* d_out, int out_size, void* d_ws, size_t ws_size,
                              hipStream_t stream)
{
    const int*   x    = (const int*)d_in[0];
    const float* embW = (const float*)d_in[1];
    const float* Wih  = (const float*)d_in[2];
    const float* Whh  = (const float*)d_in[3];
    const float* bih  = (const float*)d_in[4];
    const float* bhh  = (const float*)d_in[5];
    const float* decb = (const float*)d_in[6];
    float* out = (float*)d_out;

    char* p = (char*)d_ws;
    auto carve = [&](size_t bytes) {
        char* q = p;
        p += (bytes + 255) & ~(size_t)255;
        return q;
    };
    u16*   embW_bf = (u16*)carve((size_t)VOCAB * KDIM * 2);   // 98.2 MB
    u16*   Wih_bf  = (u16*)carve((size_t)4096 * KDIM * 2);    // 8 MB
    u16*   Whh_bf  = (u16*)carve((size_t)4096 * KDIM * 2);    // 8 MB
    u16*   emb_bf  = (u16*)carve((size_t)MROWS * KDIM * 2);   // 4 MB
    float* xproj   = (float*)carve((size_t)MROWS * 4096 * 4); // 33.6 MB
    u16*   hall_bf = (u16*)carve((size_t)MROWS * KDIM * 2);   // 4 MB
    u16*   hbuf    = (u16*)carve((size_t)2 * 16 * KDIM * 2);  // 64 KB
    float* bsum    = (float*)carve((size_t)4096 * 4);
    u32*   cnt     = (u32*)carve(256);

    hipMemsetAsync(hbuf, 0, 2 * 16 * KDIM * 2, stream);
    hipMemsetAsync(cnt, 0, 4, stream);

    conv_bf16<<<1024, 256, 0, stream>>>((const float4*)Wih, (ushort4*)Wih_bf,
                                        (long)4096 * KDIM / 4);
    conv_bf16<<<1024, 256, 0, stream>>>((const float4*)Whh, (ushort4*)Whh_bf,
                                        (long)4096 * KDIM / 4);
    conv_bf16<<<2048, 256, 0, stream>>>((const float4*)embW, (ushort4*)embW_bf,
                                        (long)VOCAB * KDIM / 4);
    bias_sum<<<16, 256, 0, stream>>>(bih, bhh, bsum);
    gather_emb<<<MROWS, 256, 0, stream>>>(x, embW, emb_bf);

    // x_proj = emb * W_ih^T + (b_ih + b_hh)
    {
        dim3 g(MROWS / BM, 4096 / BN);
        gemm_bt<<<g, 256, 0, stream>>>(emb_bf, Wih_bf, bsum, xproj, 4096, 4096, KDIM, 4096);
    }

    // LSTM recurrence: single persistent kernel, internal grid sync per step
    lstm_persist<<<NBLK, 256, 0, stream>>>(Whh_bf, xproj, hbuf, hall_bf,
                                           out + LOGN, cnt);

    // logits = h_all * embW^T + dec_b
    {
        dim3 g(MROWS / BM, (VOCAB + BN - 1) / BN);
        gemm_bt<<<g, 256, 0, stream>>>(hall_bf, embW_bf, decb, out, VOCAB, VOCAB, KDIM, VOCAB);
    }

    logsoftmax_rows<<<MROWS, 256, 0, stream>>>(out);
}

// Round 3
// 2137.446 us; speedup vs baseline: 1.8355x; 1.8355x over previous
//
#include <hip/hip_runtime.h>

typedef float f32x4 __attribute__((ext_vector_type(4)));
typedef __bf16 bf16x8 __attribute__((ext_vector_type(8)));
typedef unsigned short u16;
typedef unsigned int u32;

#define VOCAB 50257
#define KDIM 1024
#define MROWS 2048
#define TSEQ 256
#define NBLK 64
#define LOGN ((size_t)MROWS * VOCAB)

__device__ __forceinline__ u16 f2bf(float f) {
    u32 u = __builtin_bit_cast(u32, f);
    u = (u + 0x7FFFu + ((u >> 16) & 1u)) >> 16;
    return (u16)u;
}

__device__ __forceinline__ float sigm(float x) { return 1.0f / (1.0f + __expf(-x)); }

// ---------------- conversions / small prep ----------------

__global__ void conv_bf16(const float4* __restrict__ in, ushort4* __restrict__ out, long n4) {
    long i = (long)blockIdx.x * blockDim.x + threadIdx.x;
    long stride = (long)gridDim.x * blockDim.x;
    for (; i < n4; i += stride) {
        float4 v = in[i];
        ushort4 o;
        o.x = f2bf(v.x); o.y = f2bf(v.y); o.z = f2bf(v.z); o.w = f2bf(v.w);
        out[i] = o;
    }
}

__global__ void bias_sum(const float* __restrict__ a, const float* __restrict__ b,
                         float* __restrict__ o) {
    int i = blockIdx.x * 256 + threadIdx.x;
    if (i < 4096) o[i] = a[i] + b[i];
}

__global__ __launch_bounds__(256) void gather_emb(const int* __restrict__ x,
                                                  const float* __restrict__ embW,
                                                  u16* __restrict__ out) {
    int m = blockIdx.x;
    int row = x[m];
    const float4* src = (const float4*)(embW + (size_t)row * KDIM);
    ushort4* dst = (ushort4*)(out + (size_t)m * KDIM);
    float4 v = src[threadIdx.x];
    ushort4 o;
    o.x = f2bf(v.x); o.y = f2bf(v.y); o.z = f2bf(v.z); o.w = f2bf(v.w);
    dst[threadIdx.x] = o;
}

// ---------------- bf16 MFMA GEMM (C = A * B^T + bias), BK=64, swizzled LDS ----------------

#define BM 128
#define BN 128
#define BK 64

__device__ __forceinline__ void gl_lds16(const u16* g, const u16* l) {
    __builtin_amdgcn_global_load_lds(
        (const __attribute__((address_space(1))) u32*)g,
        (__attribute__((address_space(3))) u32*)l, 16, 0, 0);
}

__global__ __launch_bounds__(256, 2)
void gemm_bt(const u16* __restrict__ A, const u16* __restrict__ Bm,
             const float* __restrict__ bias, float* __restrict__ C,
             int N, int Nb, int K, int ldc)
{
    __shared__ __align__(16) u16 As[BM * BK];   // 16 KB
    __shared__ __align__(16) u16 Bs[BN * BK];   // 16 KB
    const int tid  = threadIdx.x;
    const int lane = tid & 63;
    const int wid  = tid >> 6;

    // bijective XCD swizzle (T1, m204)
    const int gx  = gridDim.x;
    const int nwg = gx * gridDim.y;
    const int lin = blockIdx.y * gx + blockIdx.x;
    const int qq = nwg >> 3, rr = nwg & 7;
    const int xcd = lin & 7, idx = lin >> 3;
    const int neu = (xcd < rr) ? (xcd * (qq + 1) + idx)
                               : (rr * (qq + 1) + (xcd - rr) * qq + idx);
    const int bm = neu % gx;
    const int bn = neu / gx;

    const int wr = wid >> 1, wc = wid & 1;

    const u16* gA[4]; const u16* gB[4];
    const u16* ldsA[4]; const u16* ldsB[4];
#pragma unroll
    for (int r = 0; r < 4; ++r) {
        int L = r * 256 + tid;
        int row = L >> 3, ps = L & 7;
        int ls = ps ^ (row & 7);
        gA[r] = A + (size_t)(bm * BM + row) * K + ls * 8;
        int brow = bn * BN + row; brow = brow < Nb ? brow : Nb - 1;
        gB[r] = Bm + (size_t)brow * K + ls * 8;
        ldsA[r] = As + (r * 256 + wid * 64) * 8;
        ldsB[r] = Bs + (r * 256 + wid * 64) * 8;
    }

    const int lrow = lane & 15, ksl = lane >> 4;
    int aoff[4][2], boff[4][2];
#pragma unroll
    for (int i = 0; i < 4; ++i)
#pragma unroll
        for (int ks = 0; ks < 2; ++ks) {
            int ar = wr * 64 + i * 16 + lrow;
            aoff[i][ks] = ar * BK + (((ks * 4 + ksl) ^ (ar & 7)) * 8);
            int br = wc * 64 + i * 16 + lrow;
            boff[i][ks] = br * BK + (((ks * 4 + ksl) ^ (br & 7)) * 8);
        }

    f32x4 acc[4][4] = {};
    for (int kt = 0; kt < K; kt += BK) {
#pragma unroll
        for (int r = 0; r < 4; ++r) gl_lds16(gA[r] + kt, ldsA[r]);
#pragma unroll
        for (int r = 0; r < 4; ++r) gl_lds16(gB[r] + kt, ldsB[r]);
        __syncthreads();
        bf16x8 af[4][2], bfb[4][2];
#pragma unroll
        for (int i = 0; i < 4; ++i)
#pragma unroll
            for (int ks = 0; ks < 2; ++ks) {
                af[i][ks]  = *(const bf16x8*)(As + aoff[i][ks]);
                bfb[i][ks] = *(const bf16x8*)(Bs + boff[i][ks]);
            }
#pragma unroll
        for (int ks = 0; ks < 2; ++ks)
#pragma unroll
            for (int mi = 0; mi < 4; ++mi)
#pragma unroll
                for (int ni = 0; ni < 4; ++ni)
                    acc[mi][ni] = __builtin_amdgcn_mfma_f32_16x16x32_bf16(
                        af[mi][ks], bfb[ni][ks], acc[mi][ni], 0, 0, 0);
        __syncthreads();
    }

    const int crl = lane >> 4, ccl = lane & 15;
    const int row0 = bm * BM + wr * 64, col0 = bn * BN + wc * 64;
#pragma unroll
    for (int ni = 0; ni < 4; ++ni) {
        int col = col0 + ni * 16 + ccl;
        if (col < N) {
            float bv = bias[col];
#pragma unroll
            for (int mi = 0; mi < 4; ++mi) {
                int row = row0 + mi * 16 + crl * 4;
                float* cp = C + (size_t)row * ldc + col;
#pragma unroll
                for (int r = 0; r < 4; ++r)
                    cp[(size_t)r * ldc] = acc[mi][ni][r] + bv;
            }
        }
    }
}

// ---------------- persistent LSTM: 64 blocks, cheap flag barrier per step ----------------
// Block b owns h-columns [16b,16b+16). Wave q = gate quadrant; 16 Whh rows/wave
// pinned in 128 VGPRs via inline-asm loads (un-sinkable).
// h layout: hbuf2[2][64 j][16 row][16 col] bf16; rows 8..15 permanently zero.
// h stores = relaxed device-scope u32 atomics (coherence point, no L2 dirty);
// barrier = per-block flag lines + relaxed poll + one acquire fence per step.

__global__ __launch_bounds__(256, 1)
void lstm_persist(const u16* __restrict__ Whh,     // [4096][1024] bf16
                  const float* __restrict__ xproj, // [2048][4096] f32
                  u16* __restrict__ hbuf2,         // [2][64][16][16] bf16 (zeroed)
                  u16* __restrict__ hall,          // [2048][1024] bf16
                  float* __restrict__ outTail,     // h[8][1024], c[8][1024] f32
                  u32* __restrict__ flags)         // [64][32] (zeroed)
{
    const int tid  = threadIdx.x;
    const int lane = tid & 63;
    const int wq   = tid >> 6;                 // gate quadrant (i,f,g,o)
    const int lrow = lane & 15, ksl = lane >> 4;
    const int bid  = blockIdx.x;
    const int colbase = bid * 16;

    // persistent Whh fragments: 32 x bf16x8 = 128 VGPRs, pinned via volatile asm
    bf16x8 Bf[32];
    {
        const u16* bp = Whh + (size_t)(wq * 1024 + colbase + lrow) * KDIM + ksl * 8;
#pragma unroll
        for (int kk = 0; kk < 32; ++kk)
            asm volatile("global_load_dwordx4 %0, %1, off"
                         : "=v"(Bf[kk]) : "v"(bp + kk * 32));
        asm volatile("s_waitcnt vmcnt(0)" ::: "memory");
        __builtin_amdgcn_sched_barrier(0);
    }

    __shared__ float S[4][8][16];

    const bool upd = tid < 128;
    const int b8 = tid >> 4, c16 = tid & 15;
    float creg = 0.f;
    float xp0 = 0.f, xp1 = 0.f, xp2 = 0.f, xp3 = 0.f;
    size_t xbase = 0;
    if (upd) {
        xbase = (size_t)b8 * TSEQ * 4096 + colbase + c16;
        xp0 = xproj[xbase];          xp1 = xproj[xbase + 1024];
        xp2 = xproj[xbase + 2048];   xp3 = xproj[xbase + 3072];
    }

    // A-fragment base: element (batch=lrow, k=kk*32+ksl*8+e) lives at
    // j*256 + lrow*16 + c, j = 2kk + (ksl>>1), c = (ksl&1)*8 + e
    const u16* abase0 = hbuf2 + (ksl >> 1) * 256 + lrow * 16 + (ksl & 1) * 8;

    for (int t = 0; t < TSEQ; ++t) {
        const u16* ab = abase0 + (t & 1) * 16384;
        f32x4 ac0 = {}, ac1 = {}, ac2 = {}, ac3 = {};
#pragma unroll
        for (int kk = 0; kk < 32; kk += 4) {
            bf16x8 a0 = *(const bf16x8*)(ab + (size_t)(kk + 0) * 512);
            bf16x8 a1 = *(const bf16x8*)(ab + (size_t)(kk + 1) * 512);
            bf16x8 a2 = *(const bf16x8*)(ab + (size_t)(kk + 2) * 512);
            bf16x8 a3 = *(const bf16x8*)(ab + (size_t)(kk + 3) * 512);
            ac0 = __builtin_amdgcn_mfma_f32_16x16x32_bf16(a0, Bf[kk + 0], ac0, 0, 0, 0);
            ac1 = __builtin_amdgcn_mfma_f32_16x16x32_bf16(a1, Bf[kk + 1], ac1, 0, 0, 0);
            ac2 = __builtin_amdgcn_mfma_f32_16x16x32_bf16(a2, Bf[kk + 2], ac2, 0, 0, 0);
            ac3 = __builtin_amdgcn_mfma_f32_16x16x32_bf16(a3, Bf[kk + 3], ac3, 0, 0, 0);
        }
        if (ksl < 2) {
#pragma unroll
            for (int r = 0; r < 4; ++r)
                S[wq][ksl * 4 + r][lrow] = ac0[r] + ac1[r] + ac2[r] + ac3[r];
        }
        __syncthreads();
        if (upd) {
            float gi = S[0][b8][c16] + xp0;
            float gf = S[1][b8][c16] + xp1;
            float gg = S[2][b8][c16] + xp2;
            float go = S[3][b8][c16] + xp3;
            float iv = sigm(gi), fv = sigm(gf), ov = sigm(go);
            float gv = tanhf(gg);
            creg = fv * creg + iv * gv;
            float hv = ov * tanhf(creg);
            u16 hb = f2bf(hv);
            hall[((size_t)b8 * TSEQ + t) * KDIM + colbase + c16] = hb;
            int w0 = (int)hb;
            int w1 = __shfl_down(w0, 1);       // neighbor col's bf16
            if (!(c16 & 1)) {
                u32 w = (u32)(u16)w0 | ((u32)(u16)w1 << 16);
                u32* dst = (u32*)hbuf2 + ((t + 1) & 1) * 8192 + bid * 128 + b8 * 8 + (c16 >> 1);
                __hip_atomic_store(dst, w, __ATOMIC_RELAXED, __HIP_MEMORY_SCOPE_AGENT);
            }
            if (t == TSEQ - 1) {
                outTail[b8 * KDIM + colbase + c16] = hv;
                outTail[8192 + b8 * KDIM + colbase + c16] = creg;
            }
            int tn = (t + 1 < TSEQ) ? t + 1 : t;
            size_t xb = xbase + (size_t)tn * 4096;
            xp0 = xproj[xb];        xp1 = xproj[xb + 1024];
            xp2 = xproj[xb + 2048]; xp3 = xproj[xb + 3072];
        }
        __syncthreads();   // drains vmcnt: all h atomic stores at coherence point
        if (tid == 0)
            __hip_atomic_store(flags + bid * 32, (u32)(t + 1),
                               __ATOMIC_RELAXED, __HIP_MEMORY_SCOPE_AGENT);
        if (tid < NBLK) {
            while (__hip_atomic_load(flags + tid * 32, __ATOMIC_RELAXED,
                                     __HIP_MEMORY_SCOPE_AGENT) < (u32)(t + 1))
                __builtin_amdgcn_s_sleep(2);
        }
        __builtin_amdgcn_fence(__ATOMIC_ACQUIRE, "agent");  // one inv per step
        __syncthreads();
    }
}

// ---------------- log_softmax: 2-pass (online max+sum, then subtract) ----------------

__global__ __launch_bounds__(256)
void logsoftmax_rows(float* __restrict__ out) {
    const int m = blockIdx.x;
    float* row = out + (size_t)m * VOCAB;
    const int tid = threadIdx.x;
    __shared__ float smx[4], ssm[4], slse;

    const int head = (int)(((16 - ((uintptr_t)row & 15)) & 15) >> 2);
    const int nv = (VOCAB - head) >> 2;
    const int tail0 = head + nv * 4;
    const int ntail = VOCAB - tail0;
    const float4* rv = (const float4*)(row + head);

    float mx = -3.0e38f, s = 0.f;
    for (int i = tid; i < nv; i += 256) {
        float4 v = rv[i];
        float m4 = fmaxf(fmaxf(v.x, v.y), fmaxf(v.z, v.w));
        if (m4 > mx) { s *= __expf(mx - m4); mx = m4; }
        s += __expf(v.x - mx) + __expf(v.y - mx) + __expf(v.z - mx) + __expf(v.w - mx);
    }
    if (tid < head) {
        float v = row[tid];
        if (v > mx) { s *= __expf(mx - v); mx = v; }
        s += __expf(v - mx);
    }
    if (tid >= 64 && tid < 64 + ntail) {
        float v = row[tail0 + (tid - 64)];
        if (v > mx) { s *= __expf(mx - v); mx = v; }
        s += __expf(v - mx);
    }
#pragma unroll
    for (int off = 32; off > 0; off >>= 1) {
        float om = __shfl_xor(mx, off), os = __shfl_xor(s, off);
        float nm = fmaxf(mx, om);
        s = s * __expf(mx - nm) + os * __expf(om - nm);
        mx = nm;
    }
    if ((tid & 63) == 0) { smx[tid >> 6] = mx; ssm[tid >> 6] = s; }
    __syncthreads();
    if (tid == 0) {
        float M = fmaxf(fmaxf(smx[0], smx[1]), fmaxf(smx[2], smx[3]));
        float S4 = ssm[0] * __expf(smx[0] - M) + ssm[1] * __expf(smx[1] - M) +
                   ssm[2] * __expf(smx[2] - M) + ssm[3] * __expf(smx[3] - M);
        slse = M + __logf(S4);
    }
    __syncthreads();
    const float lse = slse;

    float4* wv = (float4*)(row + head);
    for (int i = tid; i < nv; i += 256) {
        float4 v = rv[i];
        v.x -= lse; v.y -= lse; v.z -= lse; v.w -= lse;
        wv[i] = v;
    }
    if (tid < head) row[tid] -= lse;
    if (tid >= 64 && tid < 64 + ntail) row[tail0 + (tid - 64)] -= lse;
}

// ---------------- host ----------------

extern "C" void kernel_launch(void* const* d_in, const int* in_sizes, int n_in,
                              void* d_out, int out_size, void* d_ws, size_t ws_size,
                              hipStream_t stream)
{
    const int*   x    = (const int*)d_in[0];
    const float* embW = (const float*)d_in[1];
    const float* Wih  = (const float*)d_in[2];
    const float* Whh  = (const float*)d_in[3];
    const float* bih  = (const float*)d_in[4];
    const float* bhh  = (const float*)d_in[5];
    const float* decb = (const float*)d_in[6];
    float* out = (float*)d_out;

    char* p = (char*)d_ws;
    auto carve = [&](size_t bytes) {
        char* q = p;
        p += (bytes + 255) & ~(size_t)255;
        return q;
    };
    u16*   embW_bf = (u16*)carve((size_t)VOCAB * KDIM * 2);   // 98.2 MB
    u16*   Wih_bf  = (u16*)carve((size_t)4096 * KDIM * 2);    // 8 MB
    u16*   Whh_bf  = (u16*)carve((size_t)4096 * KDIM * 2);    // 8 MB
    u16*   emb_bf  = (u16*)carve((size_t)MROWS * KDIM * 2);   // 4 MB
    float* xproj   = (float*)carve((size_t)MROWS * 4096 * 4); // 33.6 MB
    u16*   hall_bf = (u16*)carve((size_t)MROWS * KDIM * 2);   // 4 MB
    u16*   hbuf2   = (u16*)carve((size_t)2 * 64 * 16 * 16 * 2); // 64 KB
    float* bsum    = (float*)carve((size_t)4096 * 4);
    u32*   flags   = (u32*)carve((size_t)NBLK * 32 * 4);      // 8 KB

    hipMemsetAsync(hbuf2, 0, (size_t)2 * 64 * 16 * 16 * 2, stream);
    hipMemsetAsync(flags, 0, (size_t)NBLK * 32 * 4, stream);

    conv_bf16<<<1024, 256, 0, stream>>>((const float4*)Wih, (ushort4*)Wih_bf,
                                        (long)4096 * KDIM / 4);
    conv_bf16<<<1024, 256, 0, stream>>>((const float4*)Whh, (ushort4*)Whh_bf,
                                        (long)4096 * KDIM / 4);
    conv_bf16<<<2048, 256, 0, stream>>>((const float4*)embW, (ushort4*)embW_bf,
                                        (long)VOCAB * KDIM / 4);
    bias_sum<<<16, 256, 0, stream>>>(bih, bhh, bsum);
    gather_emb<<<MROWS, 256, 0, stream>>>(x, embW, emb_bf);

    // x_proj = emb * W_ih^T + (b_ih + b_hh)
    {
        dim3 g(MROWS / BM, 4096 / BN);
        gemm_bt<<<g, 256, 0, stream>>>(emb_bf, Wih_bf, bsum, xproj, 4096, 4096, KDIM, 4096);
    }

    // LSTM recurrence: single persistent kernel, flag barrier per step
    lstm_persist<<<NBLK, 256, 0, stream>>>(Whh_bf, xproj, hbuf2, hall_bf,
                                           out + LOGN, flags);

    // logits = h_all * embW^T + dec_b
    {
        dim3 g(MROWS / BM, (VOCAB + BN - 1) / BN);
        gemm_bt<<<g, 256, 0, stream>>>(hall_bf, embW_bf, decb, out, VOCAB, VOCAB, KDIM, VOCAB);
    }

    logsoftmax_rows<<<MROWS, 256, 0, stream>>>(out);
}

// Round 4
// 1408.452 us; speedup vs baseline: 2.7855x; 1.5176x over previous
//
#include <hip/hip_runtime.h>

typedef float f32x4 __attribute__((ext_vector_type(4)));
typedef __bf16 bf16x8 __attribute__((ext_vector_type(8)));
typedef unsigned short u16;
typedef unsigned int u32;

#define VOCAB 50257
#define KDIM 1024
#define MROWS 2048
#define TSEQ 256
#define NBLK 64
#define LOGN ((size_t)MROWS * VOCAB)

__device__ __forceinline__ u16 f2bf(float f) {
    u32 u = __builtin_bit_cast(u32, f);
    u = (u + 0x7FFFu + ((u >> 16) & 1u)) >> 16;
    return (u16)u;
}

__device__ __forceinline__ float sigm(float x) { return 1.0f / (1.0f + __expf(-x)); }

// ---------------- conversions / small prep ----------------

__global__ void conv_bf16(const float4* __restrict__ in, ushort4* __restrict__ out, long n4) {
    long i = (long)blockIdx.x * blockDim.x + threadIdx.x;
    long stride = (long)gridDim.x * blockDim.x;
    for (; i < n4; i += stride) {
        float4 v = in[i];
        ushort4 o;
        o.x = f2bf(v.x); o.y = f2bf(v.y); o.z = f2bf(v.z); o.w = f2bf(v.w);
        out[i] = o;
    }
}

__global__ void bias_sum(const float* __restrict__ a, const float* __restrict__ b,
                         float* __restrict__ o) {
    int i = blockIdx.x * 256 + threadIdx.x;
    if (i < 4096) o[i] = a[i] + b[i];
}

__global__ __launch_bounds__(256) void gather_emb(const int* __restrict__ x,
                                                  const float* __restrict__ embW,
                                                  u16* __restrict__ out) {
    int m = blockIdx.x;
    int row = x[m];
    const float4* src = (const float4*)(embW + (size_t)row * KDIM);
    ushort4* dst = (ushort4*)(out + (size_t)m * KDIM);
    float4 v = src[threadIdx.x];
    ushort4 o;
    o.x = f2bf(v.x); o.y = f2bf(v.y); o.z = f2bf(v.z); o.w = f2bf(v.w);
    dst[threadIdx.x] = o;
}

// ---------------- bf16 MFMA GEMM (C = A * B^T + bias), BK=64, swizzled LDS ----------------

#define BM 128
#define BN 128
#define BK 64

__device__ __forceinline__ void gl_lds16(const u16* g, const u16* l) {
    __builtin_amdgcn_global_load_lds(
        (const __attribute__((address_space(1))) u32*)g,
        (__attribute__((address_space(3))) u32*)l, 16, 0, 0);
}

__global__ __launch_bounds__(256, 2)
void gemm_bt(const u16* __restrict__ A, const u16* __restrict__ Bm,
             const float* __restrict__ bias, float* __restrict__ C,
             int N, int Nb, int K, int ldc)
{
    __shared__ __align__(16) u16 As[BM * BK];   // 16 KB
    __shared__ __align__(16) u16 Bs[BN * BK];   // 16 KB
    const int tid  = threadIdx.x;
    const int lane = tid & 63;
    const int wid  = tid >> 6;

    // bijective XCD swizzle (T1, m204)
    const int gx  = gridDim.x;
    const int nwg = gx * gridDim.y;
    const int lin = blockIdx.y * gx + blockIdx.x;
    const int qq = nwg >> 3, rr = nwg & 7;
    const int xcd = lin & 7, idx = lin >> 3;
    const int neu = (xcd < rr) ? (xcd * (qq + 1) + idx)
                               : (rr * (qq + 1) + (xcd - rr) * qq + idx);
    const int bm = neu % gx;
    const int bn = neu / gx;

    const int wr = wid >> 1, wc = wid & 1;

    const u16* gA[4]; const u16* gB[4];
    const u16* ldsA[4]; const u16* ldsB[4];
#pragma unroll
    for (int r = 0; r < 4; ++r) {
        int L = r * 256 + tid;
        int row = L >> 3, ps = L & 7;
        int ls = ps ^ (row & 7);
        gA[r] = A + (size_t)(bm * BM + row) * K + ls * 8;
        int brow = bn * BN + row; brow = brow < Nb ? brow : Nb - 1;
        gB[r] = Bm + (size_t)brow * K + ls * 8;
        ldsA[r] = As + (r * 256 + wid * 64) * 8;
        ldsB[r] = Bs + (r * 256 + wid * 64) * 8;
    }

    const int lrow = lane & 15, ksl = lane >> 4;
    int aoff[4][2], boff[4][2];
#pragma unroll
    for (int i = 0; i < 4; ++i)
#pragma unroll
        for (int ks = 0; ks < 2; ++ks) {
            int ar = wr * 64 + i * 16 + lrow;
            aoff[i][ks] = ar * BK + (((ks * 4 + ksl) ^ (ar & 7)) * 8);
            int br = wc * 64 + i * 16 + lrow;
            boff[i][ks] = br * BK + (((ks * 4 + ksl) ^ (br & 7)) * 8);
        }

    f32x4 acc[4][4] = {};
    for (int kt = 0; kt < K; kt += BK) {
#pragma unroll
        for (int r = 0; r < 4; ++r) gl_lds16(gA[r] + kt, ldsA[r]);
#pragma unroll
        for (int r = 0; r < 4; ++r) gl_lds16(gB[r] + kt, ldsB[r]);
        __syncthreads();
        bf16x8 af[4][2], bfb[4][2];
#pragma unroll
        for (int i = 0; i < 4; ++i)
#pragma unroll
            for (int ks = 0; ks < 2; ++ks) {
                af[i][ks]  = *(const bf16x8*)(As + aoff[i][ks]);
                bfb[i][ks] = *(const bf16x8*)(Bs + boff[i][ks]);
            }
#pragma unroll
        for (int ks = 0; ks < 2; ++ks)
#pragma unroll
            for (int mi = 0; mi < 4; ++mi)
#pragma unroll
                for (int ni = 0; ni < 4; ++ni)
                    acc[mi][ni] = __builtin_amdgcn_mfma_f32_16x16x32_bf16(
                        af[mi][ks], bfb[ni][ks], acc[mi][ni], 0, 0, 0);
        __syncthreads();
    }

    const int crl = lane >> 4, ccl = lane & 15;
    const int row0 = bm * BM + wr * 64, col0 = bn * BN + wc * 64;
#pragma unroll
    for (int ni = 0; ni < 4; ++ni) {
        int col = col0 + ni * 16 + ccl;
        if (col < N) {
            float bv = bias[col];
#pragma unroll
            for (int mi = 0; mi < 4; ++mi) {
                int row = row0 + mi * 16 + crl * 4;
                float* cp = C + (size_t)row * ldc + col;
#pragma unroll
                for (int r = 0; r < 4; ++r)
                    cp[(size_t)r * ldc] = acc[mi][ni][r] + bv;
            }
        }
    }
}

// ---------------- persistent LSTM: 64 blocks, fence-free message passing ----------------
// Block b owns h-columns [16b,16b+16). Wave q = gate quadrant; 16 Whh rows/wave
// pinned in 128 regs via inline-asm loads. h exchange: relaxed agent-scope
// atomic stores (write-through to coherence point) -> per-block flag (relaxed)
// -> consumers read h with sc0/sc1 bypass loads. NO fences, no L2 invalidates.

__global__ __launch_bounds__(256, 1)
void lstm_persist(const u16* __restrict__ Whh,     // [4096][1024] bf16
                  const float* __restrict__ xproj, // [2048][4096] f32
                  u16* __restrict__ hbuf2,         // [2][64][16][16] bf16 (zeroed)
                  u16* __restrict__ hall,          // [2048][1024] bf16
                  float* __restrict__ outTail,     // h[8][1024], c[8][1024] f32
                  u32* __restrict__ flags)         // [64][32] (zeroed)
{
    const int tid  = threadIdx.x;
    const int lane = tid & 63;
    const int wq   = tid >> 6;                 // gate quadrant (i,f,g,o)
    const int lrow = lane & 15, ksl = lane >> 4;
    const int bid  = blockIdx.x;
    const int colbase = bid * 16;

    // persistent Whh fragments: 32 x bf16x8, pinned via volatile asm
    bf16x8 Bf[32];
    {
        const u16* bp = Whh + (size_t)(wq * 1024 + colbase + lrow) * KDIM + ksl * 8;
#pragma unroll
        for (int kk = 0; kk < 32; ++kk)
            asm volatile("global_load_dwordx4 %0, %1, off"
                         : "=v"(Bf[kk]) : "v"(bp + kk * 32));
        asm volatile("s_waitcnt vmcnt(0)" ::: "memory");
        __builtin_amdgcn_sched_barrier(0);
    }

    __shared__ float S[4][8][16];

    const bool upd = tid < 128;
    const int b8 = tid >> 4, c16 = tid & 15;
    float creg = 0.f;
    float xp0 = 0.f, xp1 = 0.f, xp2 = 0.f, xp3 = 0.f;
    size_t xbase = 0;
    if (upd) {
        xbase = (size_t)b8 * TSEQ * 4096 + colbase + c16;
        xp0 = xproj[xbase];          xp1 = xproj[xbase + 1024];
        xp2 = xproj[xbase + 2048];   xp3 = xproj[xbase + 3072];
    }

    // A-fragment base: element (batch=lrow, k=kk*32+ksl*8+e) lives at
    // j*256 + lrow*16 + c, j = 2kk + (ksl>>1), c = (ksl&1)*8 + e
    const u16* abase0 = hbuf2 + (ksl >> 1) * 256 + lrow * 16 + (ksl & 1) * 8;

    for (int t = 0; t < TSEQ; ++t) {
        const u16* ab = abase0 + (t & 1) * 16384;
        f32x4 ac0 = {}, ac1 = {}, ac2 = {}, ac3 = {};
        // coherent (L1/L2-bypass) h loads, 8 groups of 4, 2-deep pipeline
        bf16x8 AB[2][4];
#pragma unroll
        for (int i = 0; i < 4; ++i)
            asm volatile("global_load_dwordx4 %0, %1, off sc0 sc1"
                         : "=v"(AB[0][i]) : "v"(ab + (size_t)i * 512));
#pragma unroll
        for (int i = 0; i < 4; ++i)
            asm volatile("global_load_dwordx4 %0, %1, off sc0 sc1"
                         : "=v"(AB[1][i]) : "v"(ab + (size_t)(4 + i) * 512));
#pragma unroll
        for (int g = 0; g < 8; ++g) {
            if (g < 7) asm volatile("s_waitcnt vmcnt(4)" ::: "memory");
            else       asm volatile("s_waitcnt vmcnt(0)" ::: "memory");
            __builtin_amdgcn_sched_barrier(0);
            ac0 = __builtin_amdgcn_mfma_f32_16x16x32_bf16(AB[g & 1][0], Bf[g * 4 + 0], ac0, 0, 0, 0);
            ac1 = __builtin_amdgcn_mfma_f32_16x16x32_bf16(AB[g & 1][1], Bf[g * 4 + 1], ac1, 0, 0, 0);
            ac2 = __builtin_amdgcn_mfma_f32_16x16x32_bf16(AB[g & 1][2], Bf[g * 4 + 2], ac2, 0, 0, 0);
            ac3 = __builtin_amdgcn_mfma_f32_16x16x32_bf16(AB[g & 1][3], Bf[g * 4 + 3], ac3, 0, 0, 0);
            if (g < 6) {
#pragma unroll
                for (int i = 0; i < 4; ++i)
                    asm volatile("global_load_dwordx4 %0, %1, off sc0 sc1"
                                 : "=v"(AB[g & 1][i])
                                 : "v"(ab + (size_t)((g + 2) * 4 + i) * 512));
            }
        }
        if (ksl < 2) {
#pragma unroll
            for (int r = 0; r < 4; ++r)
                S[wq][ksl * 4 + r][lrow] = ac0[r] + ac1[r] + ac2[r] + ac3[r];
        }
        __syncthreads();

        float hv = 0.f;
        u16 hb = 0;
        if (upd) {
            float gi = S[0][b8][c16] + xp0;
            float gf = S[1][b8][c16] + xp1;
            float gg = S[2][b8][c16] + xp2;
            float go = S[3][b8][c16] + xp3;
            float iv = sigm(gi), fv = sigm(gf), ov = sigm(go);
            float gv = tanhf(gg);
            creg = fv * creg + iv * gv;
            hv = ov * tanhf(creg);
            hb = f2bf(hv);
            int w0 = (int)hb;
            int w1 = __shfl_down(w0, 1);
            if (!(c16 & 1)) {
                u32 w = (u32)(u16)w0 | ((u32)(u16)w1 << 16);
                u32* dst = (u32*)hbuf2 + ((t + 1) & 1) * 8192 + bid * 128 + b8 * 8 + (c16 >> 1);
                __hip_atomic_store(dst, w, __ATOMIC_RELAXED, __HIP_MEMORY_SCOPE_AGENT);
            }
        }
        __syncthreads();   // drains vmcnt: h stores at coherence point
        if (tid == 0)
            __hip_atomic_store(flags + bid * 32, (u32)(t + 1),
                               __ATOMIC_RELAXED, __HIP_MEMORY_SCOPE_AGENT);
        if (upd) {         // non-critical stores + prefetch overlap the poll
            hall[((size_t)b8 * TSEQ + t) * KDIM + colbase + c16] = hb;
            if (t == TSEQ - 1) {
                outTail[b8 * KDIM + colbase + c16] = hv;
                outTail[8192 + b8 * KDIM + colbase + c16] = creg;
            }
            int tn = (t + 1 < TSEQ) ? t + 1 : t;
            size_t xb = xbase + (size_t)tn * 4096;
            xp0 = xproj[xb];        xp1 = xproj[xb + 1024];
            xp2 = xproj[xb + 2048]; xp3 = xproj[xb + 3072];
        }
        if (tid < NBLK) {
            while (__hip_atomic_load(flags + tid * 32, __ATOMIC_RELAXED,
                                     __HIP_MEMORY_SCOPE_AGENT) < (u32)(t + 1))
                __builtin_amdgcn_s_sleep(1);
        }
        __syncthreads();
    }
}

// ---------------- log_softmax: 2-pass (online max+sum, then subtract) ----------------

__global__ __launch_bounds__(256)
void logsoftmax_rows(float* __restrict__ out) {
    const int m = blockIdx.x;
    float* row = out + (size_t)m * VOCAB;
    const int tid = threadIdx.x;
    __shared__ float smx[4], ssm[4], slse;

    const int head = (int)(((16 - ((uintptr_t)row & 15)) & 15) >> 2);
    const int nv = (VOCAB - head) >> 2;
    const int tail0 = head + nv * 4;
    const int ntail = VOCAB - tail0;
    const float4* rv = (const float4*)(row + head);

    float mx = -3.0e38f, s = 0.f;
    for (int i = tid; i < nv; i += 256) {
        float4 v = rv[i];
        float m4 = fmaxf(fmaxf(v.x, v.y), fmaxf(v.z, v.w));
        if (m4 > mx) { s *= __expf(mx - m4); mx = m4; }
        s += __expf(v.x - mx) + __expf(v.y - mx) + __expf(v.z - mx) + __expf(v.w - mx);
    }
    if (tid < head) {
        float v = row[tid];
        if (v > mx) { s *= __expf(mx - v); mx = v; }
        s += __expf(v - mx);
    }
    if (tid >= 64 && tid < 64 + ntail) {
        float v = row[tail0 + (tid - 64)];
        if (v > mx) { s *= __expf(mx - v); mx = v; }
        s += __expf(v - mx);
    }
#pragma unroll
    for (int off = 32; off > 0; off >>= 1) {
        float om = __shfl_xor(mx, off), os = __shfl_xor(s, off);
        float nm = fmaxf(mx, om);
        s = s * __expf(mx - nm) + os * __expf(om - nm);
        mx = nm;
    }
    if ((tid & 63) == 0) { smx[tid >> 6] = mx; ssm[tid >> 6] = s; }
    __syncthreads();
    if (tid == 0) {
        float M = fmaxf(fmaxf(smx[0], smx[1]), fmaxf(smx[2], smx[3]));
        float S4 = ssm[0] * __expf(smx[0] - M) + ssm[1] * __expf(smx[1] - M) +
                   ssm[2] * __expf(smx[2] - M) + ssm[3] * __expf(smx[3] - M);
        slse = M + __logf(S4);
    }
    __syncthreads();
    const float lse = slse;

    float4* wv = (float4*)(row + head);
    for (int i = tid; i < nv; i += 256) {
        float4 v = rv[i];
        v.x -= lse; v.y -= lse; v.z -= lse; v.w -= lse;
        wv[i] = v;
    }
    if (tid < head) row[tid] -= lse;
    if (tid >= 64 && tid < 64 + ntail) row[tail0 + (tid - 64)] -= lse;
}

// ---------------- host ----------------

extern "C" void kernel_launch(void* const* d_in, const int* in_sizes, int n_in,
                              void* d_out, int out_size, void* d_ws, size_t ws_size,
                              hipStream_t stream)
{
    const int*   x    = (const int*)d_in[0];
    const float* embW = (const float*)d_in[1];
    const float* Wih  = (const float*)d_in[2];
    const float* Whh  = (const float*)d_in[3];
    const float* bih  = (const float*)d_in[4];
    const float* bhh  = (const float*)d_in[5];
    const float* decb = (const float*)d_in[6];
    float* out = (float*)d_out;

    char* p = (char*)d_ws;
    auto carve = [&](size_t bytes) {
        char* q = p;
        p += (bytes + 255) & ~(size_t)255;
        return q;
    };
    u16*   embW_bf = (u16*)carve((size_t)VOCAB * KDIM * 2);   // 98.2 MB
    u16*   Wih_bf  = (u16*)carve((size_t)4096 * KDIM * 2);    // 8 MB
    u16*   Whh_bf  = (u16*)carve((size_t)4096 * KDIM * 2);    // 8 MB
    u16*   emb_bf  = (u16*)carve((size_t)MROWS * KDIM * 2);   // 4 MB
    float* xproj   = (float*)carve((size_t)MROWS * 4096 * 4); // 33.6 MB
    u16*   hall_bf = (u16*)carve((size_t)MROWS * KDIM * 2);   // 4 MB
    u16*   hbuf2   = (u16*)carve((size_t)2 * 64 * 16 * 16 * 2); // 64 KB
    float* bsum    = (float*)carve((size_t)4096 * 4);
    u32*   flags   = (u32*)carve((size_t)NBLK * 32 * 4);      // 8 KB

    hipMemsetAsync(hbuf2, 0, (size_t)2 * 64 * 16 * 16 * 2, stream);
    hipMemsetAsync(flags, 0, (size_t)NBLK * 32 * 4, stream);

    conv_bf16<<<1024, 256, 0, stream>>>((const float4*)Wih, (ushort4*)Wih_bf,
                                        (long)4096 * KDIM / 4);
    conv_bf16<<<1024, 256, 0, stream>>>((const float4*)Whh, (ushort4*)Whh_bf,
                                        (long)4096 * KDIM / 4);
    conv_bf16<<<2048, 256, 0, stream>>>((const float4*)embW, (ushort4*)embW_bf,
                                        (long)VOCAB * KDIM / 4);
    bias_sum<<<16, 256, 0, stream>>>(bih, bhh, bsum);
    gather_emb<<<MROWS, 256, 0, stream>>>(x, embW, emb_bf);

    // x_proj = emb * W_ih^T + (b_ih + b_hh)
    {
        dim3 g(MROWS / BM, 4096 / BN);
        gemm_bt<<<g, 256, 0, stream>>>(emb_bf, Wih_bf, bsum, xproj, 4096, 4096, KDIM, 4096);
    }

    // LSTM recurrence: single persistent kernel, fence-free flag barrier
    lstm_persist<<<NBLK, 256, 0, stream>>>(Whh_bf, xproj, hbuf2, hall_bf,
                                           out + LOGN, flags);

    // logits = h_all * embW^T + dec_b
    {
        dim3 g(MROWS / BM, (VOCAB + BN - 1) / BN);
        gemm_bt<<<g, 256, 0, stream>>>(hall_bf, embW_bf, decb, out, VOCAB, VOCAB, KDIM, VOCAB);
    }

    logsoftmax_rows<<<MROWS, 256, 0, stream>>>(out);
}